// Round 15
// baseline (1555.665 us; speedup 1.0000x reference)
//
#include <hip/hip_runtime.h>

#define QS 8
#define KC 1024
#define DD 256
#define TT 8192
#define NN 65536
#define TAU 0.06f
#define FLAGCAP 49152

typedef _Float16 half8 __attribute__((ext_vector_type(8)));
typedef float f32x4 __attribute__((ext_vector_type(4)));

// ---------------------------------------------------------------------------
// Encoder: z = conv1d(x) -> res (token-major [N][256]); zero loss + flag cnts.
// ---------------------------------------------------------------------------
__global__ __launch_bounds__(256) void encode_init_kernel(
    const float* __restrict__ x, const float* __restrict__ ew,
    const float* __restrict__ eb, float* __restrict__ res,
    float* __restrict__ lossAcc, int* __restrict__ flagCnt)
{
    if (blockIdx.x == 0 && threadIdx.x == 0) *lossAcc = 0.0f;
    if (blockIdx.x == 0 && threadIdx.x < QS) flagCnt[threadIdx.x] = 0;
    const int d = threadIdx.x;                 // 256 == DD
    const float w0 = ew[d*3 + 0];
    const float w1 = ew[d*3 + 1];
    const float w2 = ew[d*3 + 2];
    const float b  = eb[d];
    #pragma unroll 4
    for (int tt = 0; tt < 16; ++tt) {
        const long n = (long)blockIdx.x * 16 + tt;   // grid = 4096
        const int t = (int)(n & (TT - 1));
        const float xm = (t > 0)      ? x[n - 1] : 0.0f;
        const float x0 = x[n];
        const float xp = (t < TT - 1) ? x[n + 1] : 0.0f;
        res[n * DD + d] = b + w0*xm + w1*x0 + w2*xp;
    }
}

// ---------------------------------------------------------------------------
// c2[s][k] = ||codebook[s][k]||^2 ; one wave per code.
// ---------------------------------------------------------------------------
__global__ __launch_bounds__(256) void c2_kernel(
    const float* __restrict__ cbs, float* __restrict__ c2)
{
    const int w = (int)((blockIdx.x * blockDim.x + threadIdx.x) >> 6);
    const int lane = threadIdx.x & 63;
    if (w >= QS * KC) return;
    const float* row = cbs + (long)w * DD;
    float s = 0.0f;
    #pragma unroll
    for (int q = 0; q < DD / 64; ++q) {
        const float v = row[lane + 64*q];
        s += v * v;
    }
    #pragma unroll
    for (int off = 32; off; off >>= 1) s += __shfl_down(s, off, 64);
    if (lane == 0) c2[w] = s;
}

// ---------------------------------------------------------------------------
// Per-stage codebook f16, FRAGMENT-LINEAR layout for direct L2->reg reads:
// tile t = cg*4+kp (64 x 4096 f16); fragment f = kc2*4+nt (8 x 512 f16);
// lane l = l4*16+l15 holds 8 f16 at t*4096 + f*512 + l*8.
// Covers cb[cg*64 + nt*16 + l15][kp*64 + kc2*32 + l4*8 + e].
// Each wave fragment read = ONE contiguous 1KB global_load_dwordx4 burst.
// ---------------------------------------------------------------------------
__global__ __launch_bounds__(256) void cb_prep_stage_kernel(
    const float* __restrict__ cb, _Float16* __restrict__ cbh)
{
    const int t = blockIdx.x;          // grid = 64 tiles
    const int cg = t >> 2, kp = t & 3;
    #pragma unroll
    for (int q = 0; q < 2; ++q) {
        const int p = threadIdx.x + 256*q;      // chunk in [0,512)
        const int kc2 = p >> 8, rem = p & 255;
        const int nt = rem >> 6, l4v = (rem >> 4) & 3, l15v = rem & 15;
        const int code = cg*64 + nt*16 + l15v;
        const int k0 = kp*64 + kc2*32 + l4v*8;
        const float* src = &cb[(long)code*DD + k0];
        const float4 v0 = *reinterpret_cast<const float4*>(src);
        const float4 v1 = *reinterpret_cast<const float4*>(src + 4);
        half8 hv;
        hv[0]=(_Float16)v0.x; hv[1]=(_Float16)v0.y;
        hv[2]=(_Float16)v0.z; hv[3]=(_Float16)v0.w;
        hv[4]=(_Float16)v1.x; hv[5]=(_Float16)v1.y;
        hv[6]=(_Float16)v1.z; hv[7]=(_Float16)v1.w;
        *reinterpret_cast<half8*>(
            &cbh[(long)t*4096 + (kc2*4 + nt)*512 + (l4v*16 + l15v)*8]) = hv;
    }
}

// ---------------------------------------------------------------------------
// Fused RVQ stage, f16 MFMA 2-term, B STREAMED FROM L2 (no LDS, no barriers
// in the K-loop). Register ping-pong bA/bB, statically indexed; compiler
// inserts counted vmcnt from data deps. Waves fully independent.
// ---------------------------------------------------------------------------
__global__ __launch_bounds__(256, 2) void rvq_pass1_kernel(
    const float* __restrict__ cb,      // [KC][DD] fp32 (epilogue gather)
    const _Float16* __restrict__ cbh,  // [64][4096] f16 fragment-linear
    const float* __restrict__ c2,      // [KC]
    float* __restrict__ res,           // [NN][DD]
    float* __restrict__ lossAcc,
    int* __restrict__ flagCnt,         // this stage
    int* __restrict__ flagList)        // shared list, cap FLAGCAP
{
    __shared__ int idxArr[128];

    const int tid = threadIdx.x;
    const int w   = tid >> 6;
    const int l   = tid & 63;
    const int l15 = l & 15;
    const int l4  = l >> 4;
    const long n0 = (long)blockIdx.x * 128;

    // ---- orientation probe (exact arithmetic; proven rounds 5-13) ----
    int tr;
    {
        half8 pa, pb;
        #pragma unroll
        for (int e = 0; e < 8; ++e) {
            pa[e] = (_Float16)l15;
            pb[e] = (_Float16)0.03125f;
        }
        f32x4 pacc = (f32x4){0.f, 0.f, 0.f, 0.f};
        pacc = __builtin_amdgcn_mfma_f32_16x16x32_f16(pa, pb, pacc, 0, 0, 0);
        const float p1 = __shfl(pacc[1], 0, 64);
        tr = (p1 < 0.5f) ? 1 : 0;
    }

    // ---- A fragments: token = n0 + w*32 + mt*16 + l15, k-run (l>>4)*8 ----
    half8 ah[2][8], al[2][8];
    #pragma unroll
    for (int mt = 0; mt < 2; ++mt) {
      #pragma unroll
      for (int kc = 0; kc < 8; ++kc) {
        const long n = n0 + w*32 + mt*16 + l15;
        const float* p = &res[n*DD + kc*32 + l4*8];
        const float4 v0 = *reinterpret_cast<const float4*>(p);
        const float4 v1 = *reinterpret_cast<const float4*>(p + 4);
        const float xv[8] = {v0.x, v0.y, v0.z, v0.w, v1.x, v1.y, v1.z, v1.w};
        half8 hv, lv;
        #pragma unroll
        for (int e = 0; e < 8; ++e) {
            const _Float16 hh = (_Float16)xv[e];
            hv[e] = hh;
            lv[e] = (_Float16)(xv[e] - (float)hh);
        }
        ah[mt][kc] = hv; al[mt][kc] = lv;
      }
    }

    float b1[8], b2[8]; int i1[8];
    #pragma unroll
    for (int r = 0; r < 8; ++r) { b1[r] = 1e30f; b2[r] = 1e30f; i1[r] = 0; }

    f32x4 acc[2][4];
    half8 bA[8], bB[8];
    const _Float16* cbhL = cbh + l*8;   // lane-contiguous fragment reads

    auto loadF = [&](half8* buf, int t) {
        const _Float16* base = cbhL + (long)t*4096;
        #pragma unroll
        for (int f = 0; f < 8; ++f)
            buf[f] = *reinterpret_cast<const half8*>(base + f*512);
    };
    auto comp = [&](const half8* buf, int kp) {
        #pragma unroll
        for (int kc2 = 0; kc2 < 2; ++kc2) {
          const int kc = kp*2 + kc2;
          #pragma unroll
          for (int nt = 0; nt < 4; ++nt) {
            const half8 bh = buf[kc2*4 + nt];
            #pragma unroll
            for (int mt = 0; mt < 2; ++mt) {
              acc[mt][nt] = __builtin_amdgcn_mfma_f32_16x16x32_f16(ah[mt][kc], bh, acc[mt][nt], 0, 0, 0);
              acc[mt][nt] = __builtin_amdgcn_mfma_f32_16x16x32_f16(al[mt][kc], bh, acc[mt][nt], 0, 0, 0);
            }
          }
        }
    };

    loadF(bA, 0);
    for (int cg = 0; cg < 16; ++cg) {
        const int t0 = cg*4;
        #pragma unroll
        for (int mt = 0; mt < 2; ++mt)
            #pragma unroll
            for (int nt = 0; nt < 4; ++nt)
                acc[mt][nt] = (f32x4){0.f, 0.f, 0.f, 0.f};

        loadF(bB, t0 + 1);  comp(bA, 0);
        loadF(bA, t0 + 2);  comp(bB, 1);
        loadF(bB, t0 + 3);  comp(bA, 2);
        if (cg < 15) loadF(bA, t0 + 4);
        comp(bB, 3);

        if (tr == 0) {
            // token on reg side (row=l4*4+j), code on lane side (col=l15)
            #pragma unroll
            for (int nt = 0; nt < 4; ++nt) {
                const int code = cg*64 + nt*16 + l15;
                const float cc = c2[code];
                #pragma unroll
                for (int mt = 0; mt < 2; ++mt) {
                    #pragma unroll
                    for (int j = 0; j < 4; ++j) {
                        const float dist = cc - 2.0f*acc[mt][nt][j];
                        const int r = mt*4 + j;
                        if (dist < b1[r])      { b2[r] = b1[r]; b1[r] = dist; i1[r] = code; }
                        else if (dist < b2[r]) { b2[r] = dist; }
                    }
                }
            }
        } else {
            // token on lane side (l15), code on reg side (l4*4+j)
            #pragma unroll
            for (int nt = 0; nt < 4; ++nt) {
                #pragma unroll
                for (int j = 0; j < 4; ++j) {
                    const int code = cg*64 + nt*16 + l4*4 + j;
                    const float cc = c2[code];
                    #pragma unroll
                    for (int mt = 0; mt < 2; ++mt) {
                        const float dist = cc - 2.0f*acc[mt][nt][j];
                        if (dist < b1[mt])      { b2[mt] = b1[mt]; b1[mt] = dist; i1[mt] = code; }
                        else if (dist < b2[mt]) { b2[mt] = dist; }
                    }
                }
            }
        }
    }

    if (tr == 0) {
      #pragma unroll
      for (int m = 1; m < 16; m <<= 1) {
        #pragma unroll
        for (int r = 0; r < 8; ++r) {
          const float ob1 = __shfl_xor(b1[r], m, 64);
          const float ob2 = __shfl_xor(b2[r], m, 64);
          const int   oi1 = __shfl_xor(i1[r], m, 64);
          const float nb2 = fminf(fminf(b2[r], ob2), fmaxf(b1[r], ob1));
          if (ob1 < b1[r] || (ob1 == b1[r] && oi1 < i1[r])) { b1[r] = ob1; i1[r] = oi1; }
          b2[r] = nb2;
        }
      }
      if (l15 == 0) {
        #pragma unroll
        for (int mt = 0; mt < 2; ++mt)
          #pragma unroll
          for (int j = 0; j < 4; ++j) {
            const int r = mt*4 + j;
            const int row = w*32 + mt*16 + l4*4 + j;
            idxArr[row] = i1[r];
            if (b2[r] - b1[r] < TAU) {
              const int pos = atomicAdd(flagCnt, 1);
              if (pos < FLAGCAP)
                flagList[pos] = (int)(((n0 + row) << 10) | (unsigned)i1[r]);
            }
          }
      }
    } else {
      #pragma unroll
      for (int m = 16; m <= 32; m <<= 1) {
        #pragma unroll
        for (int r = 0; r < 2; ++r) {
          const float ob1 = __shfl_xor(b1[r], m, 64);
          const float ob2 = __shfl_xor(b2[r], m, 64);
          const int   oi1 = __shfl_xor(i1[r], m, 64);
          const float nb2 = fminf(fminf(b2[r], ob2), fmaxf(b1[r], ob1));
          if (ob1 < b1[r] || (ob1 == b1[r] && oi1 < i1[r])) { b1[r] = ob1; i1[r] = oi1; }
          b2[r] = nb2;
        }
      }
      if (l4 == 0) {
        #pragma unroll
        for (int mt = 0; mt < 2; ++mt) {
          const int row = w*32 + mt*16 + l15;
          idxArr[row] = i1[mt];
          if (b2[mt] - b1[mt] < TAU) {
            const int pos = atomicAdd(flagCnt, 1);
            if (pos < FLAGCAP)
              flagList[pos] = (int)(((n0 + row) << 10) | (unsigned)i1[mt]);
          }
        }
      }
    }
    __syncthreads();   // idxArr visible to all waves (only barrier in kernel)

    // residual update in place + commitment-loss partial (float4 vectorized)
    float lsum = 0.0f;
    const int rw = tid >> 6;        // row-within-quad
    const int cc4 = (tid & 63) * 4; // column base
    #pragma unroll 4
    for (int it = 0; it < 32; ++it) {
        const int r = it*4 + rw;
        const long n = n0 + r;
        const int ix = idxArr[r];
        float4 rv = *reinterpret_cast<const float4*>(&res[n*DD + cc4]);
        const float4 cv = *reinterpret_cast<const float4*>(&cb[(long)ix*DD + cc4]);
        rv.x -= cv.x; rv.y -= cv.y; rv.z -= cv.z; rv.w -= cv.w;
        *reinterpret_cast<float4*>(&res[n*DD + cc4]) = rv;
        lsum += rv.x*rv.x + rv.y*rv.y + rv.z*rv.z + rv.w*rv.w;
    }
    #pragma unroll
    for (int off = 32; off; off >>= 1) lsum += __shfl_down(lsum, off, 64);
    if (l == 0) atomicAdd(lossAcc, lsum);
}

// ---------------------------------------------------------------------------
// Exact fp32 recheck for margin-flagged tokens. Fixed grid, grid-strided.
// ---------------------------------------------------------------------------
__global__ __launch_bounds__(256) void recheck_kernel(
    const float* __restrict__ cb, const float* __restrict__ c2,
    float* __restrict__ res, float* __restrict__ lossAcc,
    const int* __restrict__ flagCnt, const int* __restrict__ flagList)
{
    __shared__ float rorig[DD];
    __shared__ float sD[256];
    __shared__ int   sI[256];
    const int cnt = min(*flagCnt, FLAGCAP);
    const int tid = threadIdx.x;
    for (int f = blockIdx.x; f < cnt; f += gridDim.x) {
        const int packed = flagList[f];
        const long n  = packed >> 10;
        const int old = packed & 1023;
        __syncthreads();   // protect LDS reuse across f-iterations
        const float rme = res[n*DD + tid] + cb[(long)old*DD + tid];
        rorig[tid] = rme;
        __syncthreads();
        float bd = 1e30f; int bi = 0;
        #pragma unroll
        for (int q = 0; q < 4; ++q) {
            const int code = tid + 256*q;
            const float* crow = &cb[(long)code*DD];
            float dot = 0.f;
            for (int d = 0; d < DD; ++d) dot += rorig[d]*crow[d];
            const float dist = c2[code] - 2.0f*dot;
            if (dist < bd || (dist == bd && code < bi)) { bd = dist; bi = code; }
        }
        sD[tid] = bd; sI[tid] = bi;
        __syncthreads();
        for (int s = 128; s; s >>= 1) {
            if (tid < s) {
                const float d2 = sD[tid + s]; const int i2 = sI[tid + s];
                if (d2 < sD[tid] || (d2 == sD[tid] && i2 < sI[tid])) { sD[tid] = d2; sI[tid] = i2; }
            }
            __syncthreads();
        }
        const int best = sI[0];
        if (best != old) {
            const float rn = rorig[tid] - cb[(long)best*DD + tid];
            const float ro = res[n*DD + tid];
            res[n*DD + tid] = rn;
            float delta = rn*rn - ro*ro;
            #pragma unroll
            for (int off = 32; off; off >>= 1) delta += __shfl_down(delta, off, 64);
            if ((tid & 63) == 0) atomicAdd(lossAcc, delta);
        }
    }
}

// ---------------------------------------------------------------------------
// Decoder: quant = z - res_final (z recomputed); conv1d to 1 channel + loss out.
// ---------------------------------------------------------------------------
__global__ __launch_bounds__(256) void decode_kernel(
    const float* __restrict__ x,  const float* __restrict__ ew,
    const float* __restrict__ eb, const float* __restrict__ res,
    const float* __restrict__ dw, const float* __restrict__ db,
    const float* __restrict__ lossAcc, float* __restrict__ out)
{
    const long n = (long)blockIdx.x * 4 + (threadIdx.x >> 6);
    const int lane = threadIdx.x & 63;
    const int t = (int)(n & (TT - 1));
    float sum = 0.0f;
    #pragma unroll
    for (int k = 0; k < 3; ++k) {
        const int tm = t + k - 1;
        if (tm < 0 || tm > TT - 1) continue;
        const long m = n + k - 1;
        const float xm = (tm > 0)      ? x[m - 1] : 0.0f;
        const float x0 = x[m];
        const float xp = (tm < TT - 1) ? x[m + 1] : 0.0f;
        #pragma unroll
        for (int q = 0; q < 4; ++q) {
            const int d = lane + 64 * q;
            const float z = eb[d] + ew[d*3]*xm + ew[d*3 + 1]*x0 + ew[d*3 + 2]*xp;
            const float quant = z - res[m * DD + d];
            sum += quant * dw[d*3 + k];
        }
    }
    #pragma unroll
    for (int off = 32; off; off >>= 1) sum += __shfl_down(sum, off, 64);
    if (lane == 0) out[n] = sum + db[0];
    if (blockIdx.x == 0 && threadIdx.x == 0)
        out[NN] = lossAcc[0] * (1.0f / ((float)NN * (float)DD));
}

// ---------------------------------------------------------------------------
// Workspace: d_ws = res 64MB + lossAcc(16B) + per-stage cbh 512KB (~64.5MB).
// d_out scratch until decode: [0..7]=flagCnt[8], [8..8199]=c2, [8200..]=flagList.
// ---------------------------------------------------------------------------
extern "C" void kernel_launch(void* const* d_in, const int* in_sizes, int n_in,
                              void* d_out, int out_size, void* d_ws, size_t ws_size,
                              hipStream_t stream)
{
    const float* x     = (const float*)d_in[0];
    const float* enc_w = (const float*)d_in[1];
    const float* enc_b = (const float*)d_in[2];
    const float* dec_w = (const float*)d_in[3];
    const float* dec_b = (const float*)d_in[4];
    const float* cbs   = (const float*)d_in[5];
    float* out = (float*)d_out;

    float*    res      = (float*)d_ws;               // [NN][DD] = 64 MB
    float*    lossAcc  = res + (size_t)NN * DD;      // 1 float (+pad)
    _Float16* cbh      = (_Float16*)(lossAcc + 4);   // [64][4096] f16 = 512 KB
    int*      flagCnt  = (int*)out;                  // [QS] in d_out
    float*    c2       = out + 8;                    // [QS*KC] in d_out
    int*      flagList = (int*)(out + 8 + QS * KC);  // cap FLAGCAP in d_out

    hipLaunchKernelGGL(encode_init_kernel, dim3(NN / 16), dim3(256), 0, stream,
                       x, enc_w, enc_b, res, lossAcc, flagCnt);
    hipLaunchKernelGGL(c2_kernel, dim3(QS * KC / 4), dim3(256), 0, stream,
                       cbs, c2);
    for (int s = 0; s < QS; ++s) {
        hipLaunchKernelGGL(cb_prep_stage_kernel, dim3(64), dim3(256), 0, stream,
                           cbs + (size_t)s * KC * DD, cbh);
        hipLaunchKernelGGL(rvq_pass1_kernel, dim3(NN / 128), dim3(256), 0, stream,
                           cbs + (size_t)s * KC * DD, cbh,
                           c2 + (size_t)s * KC,
                           res, lossAcc, flagCnt + s, flagList);
        hipLaunchKernelGGL(recheck_kernel, dim3(256), dim3(256), 0, stream,
                           cbs + (size_t)s * KC * DD,
                           c2 + (size_t)s * KC,
                           res, lossAcc, flagCnt + s, flagList);
    }
    hipLaunchKernelGGL(decode_kernel, dim3(NN / 4), dim3(256), 0, stream,
                       x, enc_w, enc_b, res, dec_w, dec_b, lossAcc, out);
}